// Round 14
// baseline (249.379 us; speedup 1.0000x reference)
//
#include <hip/hip_runtime.h>
#include <hip/hip_bf16.h>

#define GATE 512
#define NTOT 120581
#define NPAN 943          // 128-col panels
#define HALF 128          // rows per block (half of 256)

typedef __attribute__((ext_vector_type(8))) short short8;   // 8 bf16
typedef __attribute__((ext_vector_type(4))) float  f32x4;

struct GemmParams {
    const float* W[10];
    const float* p[10];
    const float* bias[10];
};

__device__ __forceinline__ short bf16bits(float x) {
    __hip_bfloat16 h = __float2bfloat16(x);   // RTNE
    return *reinterpret_cast<short*>(&h);
}

__global__ void emb_to_bf16(const float* __restrict__ emb,
                            unsigned short* __restrict__ o) {
    int i = (blockIdx.x * blockDim.x + threadIdx.x) * 8;
    f32x4 a = *(const f32x4*)(emb + i);
    f32x4 b = *(const f32x4*)(emb + i + 4);
    short8 r;
#pragma unroll
    for (int j = 0; j < 4; ++j) { r[j] = bf16bits(a[j]); r[4 + j] = bf16bits(b[j]); }
    *(short8*)(o + i) = r;
}

// PERSISTENT blocks: 512 blocks x 512 threads (8 waves). Block bid owns row
// half (bid&1) and panels p0, p0+256, ... (p0 = bid>>1), 3-4 panels each.
// A: this half's 128 rows x 512 bf16 = 128 KB staged into LDS ONCE ->
//    steady state has NO LDS writes -> ZERO barriers. MFMA waits are
//    lgkm-only (immune to vmcnt in-order poisoning).
// B: per panel, whole-K in 64 VGPR bf16 (pinned); NEXT panel's B streamed
//    4 loads/chunk across the current panel's 8 chunks -> HBM-read duty
//    cycle ~1 for the kernel's entire lifetime (fixes the burst-prologue
//    duty-cycle ~0.3 that capped r7-r13 at ~1.9 TB/s).
// Stores: fire-and-forget, never waited on.
__global__ __launch_bounds__(512, 2) void gate_gemm(GemmParams P,
                                                    const unsigned short* __restrict__ embw,
                                                    float* __restrict__ out)
{
    constexpr int kStarts[11] = {0, 1728, 1792, 38656, 38720, 75584,
                                 75648, 112512, 112576, 120576, 120581};
    __shared__ unsigned short Atile[HALF * GATE];   // 128 KB

    const int t    = threadIdx.x;
    const int lane = t & 63;
    const int wave = t >> 6;      // 8 waves: cols [wave*16, +16) of each panel
    const int lr   = lane & 15;
    const int lg   = lane >> 4;

    const int half = blockIdx.x & 1;
    const int p0   = blockIdx.x >> 1;

    // ---- one-time A stage: local rows rl = wave*16 + i, swizzled source.
    // LDS 16B-unit (rl, u=lane) holds embw[half*128+rl][(lane^(rl&7))*8 ..+8].
#pragma unroll
    for (int i = 0; i < 16; ++i) {
        const int rl = wave * 16 + i;
        const unsigned short* src =
            embw + (size_t)(half * HALF + rl) * GATE + ((lane ^ (rl & 7)) * 8);
        unsigned short* dst = &Atile[rl * GATE + lane * 8];
        __builtin_amdgcn_global_load_lds(
            (const __attribute__((address_space(1))) void*)src,
            (__attribute__((address_space(3))) void*)dst, 16, 0, 0);
    }

    // per-panel column metadata
    auto colmeta = [&](int pan, const float*& wr, float& pv, float& bv,
                       int& n, bool& valid) {
        n = pan * 128 + wave * 16 + lr;
        valid = n < NTOT;
        int nc = valid ? n : NTOT - 1;
        int tt = 0;
#pragma unroll
        for (int i = 1; i < 10; ++i) tt += (nc >= kStarts[i]);
        int rr = nc - kStarts[tt];
        wr = P.W[tt] + (size_t)rr * GATE + lg * 8;
        pv = P.p[tt][rr];
        bv = P.bias[tt][rr];
    };

    // ---- B prologue for first panel (overlaps A-stage DMA)
    short8 B0[16], B1[16];
    {
        const float* wr; float pv, bv; int n; bool v;
        colmeta(p0, wr, pv, bv, n, v);
#pragma unroll
        for (int b = 0; b < 8; ++b) {
            f32x4 r0 = *(const f32x4*)(wr + b * 64);
            f32x4 r1 = *(const f32x4*)(wr + b * 64 + 4);
            f32x4 r2 = *(const f32x4*)(wr + b * 64 + 32);
            f32x4 r3 = *(const f32x4*)(wr + b * 64 + 36);
            short8 x0, x1;
#pragma unroll
            for (int q = 0; q < 4; ++q) {
                x0[q] = bf16bits(r0[q]); x0[4 + q] = bf16bits(r1[q]);
                x1[q] = bf16bits(r2[q]); x1[4 + q] = bf16bits(r3[q]);
            }
            B0[2 * b] = x0; B0[2 * b + 1] = x1;
        }
#pragma unroll
        for (int i = 0; i < 16; ++i) asm volatile("" : "+v"(B0[i]));   // pin
    }

    asm volatile("s_waitcnt vmcnt(0)" ::: "memory");   // A stage + B0 done
    __builtin_amdgcn_s_barrier();                      // the ONLY barrier

    // ---- panel body: compute `pan` from Bcur/LDS, stream B(pnext) into Bnext
    auto body = [&](short8 (&Bcur)[16], short8 (&Bnext)[16], int pan, int pnext) {
        const float* wrc; float pv, bv; int n; bool valid;
        colmeta(pan, wrc, pv, bv, n, valid);
        const float* wrn; float pvn, bvn; int nn; bool vn;
        colmeta(pnext, wrn, pvn, bvn, nn, vn);
        float* ocol = out + n;

        f32x4 rawA[4], rawB[4];
#pragma unroll
        for (int ch = 0; ch < 8; ++ch) {
            // issue next-B loads for slots 2ch, 2ch+1 (converted next chunk)
            {
                f32x4* raw = (ch & 1) ? rawB : rawA;   // static after unroll
                raw[0] = *(const f32x4*)(wrn + ch * 64);
                raw[1] = *(const f32x4*)(wrn + ch * 64 + 4);
                raw[2] = *(const f32x4*)(wrn + ch * 64 + 32);
                raw[3] = *(const f32x4*)(wrn + ch * 64 + 36);
            }

            // compute chunk ch: rows [ch*16,+16), lgkm-only waits
            f32x4 acc0 = (f32x4){0.f, 0.f, 0.f, 0.f};
            f32x4 acc1 = (f32x4){0.f, 0.f, 0.f, 0.f};
#pragma unroll
            for (int ks = 0; ks < 16; ++ks) {
                const int slot = (ks * 4 + lg) ^ (lr & 7);
                short8 af = *(const short8*)(&Atile[(ch * 16 + lr) * GATE + slot * 8]);
                if (ks & 1) acc1 = __builtin_amdgcn_mfma_f32_16x16x32_bf16(af, Bcur[ks], acc1, 0, 0, 0);
                else        acc0 = __builtin_amdgcn_mfma_f32_16x16x32_bf16(af, Bcur[ks], acc0, 0, 0, 0);
            }

            // convert previous chunk's raws (1 chunk old) into Bnext, pin
            if (ch > 0) {
                f32x4* rp = (ch & 1) ? rawA : rawB;
                short8 x0, x1;
#pragma unroll
                for (int q = 0; q < 4; ++q) {
                    x0[q] = bf16bits(rp[0][q]); x0[4 + q] = bf16bits(rp[1][q]);
                    x1[q] = bf16bits(rp[2][q]); x1[4 + q] = bf16bits(rp[3][q]);
                }
                Bnext[2 * (ch - 1)]     = x0;
                Bnext[2 * (ch - 1) + 1] = x1;
                asm volatile("" : "+v"(Bnext[2 * (ch - 1)]), "+v"(Bnext[2 * (ch - 1) + 1]));
            }

            // stores: fire-and-forget. C/D map: col=lane&15, row=(lane>>4)*4+reg.
            if (valid) {
                const int m0 = half * HALF + ch * 16 + lg * 4;
#pragma unroll
                for (int q = 0; q < 4; ++q) {
                    float x   = acc0[q] + acc1[q] + bv;
                    float e   = __expf(-x);
                    float eta = __builtin_amdgcn_rcpf(1.0f + e);
                    ocol[(size_t)(m0 + q) * NTOT] = eta * pv;
                }
            }
        }
        // final convert (ch=7 raws live in rawB)
        {
            short8 x0, x1;
#pragma unroll
            for (int q = 0; q < 4; ++q) {
                x0[q] = bf16bits(rawB[0][q]); x0[4 + q] = bf16bits(rawB[1][q]);
                x1[q] = bf16bits(rawB[2][q]); x1[4 + q] = bf16bits(rawB[3][q]);
            }
            Bnext[14] = x0; Bnext[15] = x1;
            asm volatile("" : "+v"(Bnext[14]), "+v"(Bnext[15]));
        }
    };

    // ---- persistent panel loop (3-4 panels/block), static Bcur/Bnext roles
    int  pan  = p0;
    bool flip = false;
    while (true) {
        const int  pn   = pan + 256;
        const bool last = pn >= NPAN;
        const int  pnc  = last ? pan : pn;   // clamped prefetch (harmless reads)
        if (!flip) body(B0, B1, pan, pnc);
        else       body(B1, B0, pan, pnc);
        if (last) break;
        pan  = pn;
        flip = !flip;
    }
}

extern "C" void kernel_launch(void* const* d_in, const int* in_sizes, int n_in,
                              void* d_out, int out_size, void* d_ws, size_t ws_size,
                              hipStream_t stream) {
    const float* emb = (const float*)d_in[0];
    GemmParams P;
    for (int i = 0; i < 10; ++i) {
        P.p[i]    = (const float*)d_in[1 + 3 * i];
        P.W[i]    = (const float*)d_in[2 + 3 * i];
        P.bias[i] = (const float*)d_in[3 + 3 * i];
    }

    unsigned short* embw = (unsigned short*)d_ws;   // 256 KB, L2-resident
    emb_to_bf16<<<(256 * GATE) / (256 * 8), 256, 0, stream>>>(emb, embw);

    gate_gemm<<<512, 512, 0, stream>>>(P, embw, (float*)d_out);
}

// Round 15
// 132.499 us; speedup vs baseline: 1.8821x; 1.8821x over previous
//
#include <hip/hip_runtime.h>
#include <hip/hip_bf16.h>

#define GATE 512
#define MROWS 256
#define NTOT 120581
#define PHK 32            // K per LDS phase (16 phases)

typedef __attribute__((ext_vector_type(8))) short short8;   // 8 bf16
typedef __attribute__((ext_vector_type(4))) float  f32x4;

struct GemmParams {
    const float* W[10];
    const float* p[10];
    const float* bias[10];
};

__device__ __forceinline__ short bf16bits(float x) {
    __hip_bfloat16 h = __float2bfloat16(x);   // RTNE
    return *reinterpret_cast<short*>(&h);
}

__global__ void emb_to_bf16(const float* __restrict__ emb,
                            unsigned short* __restrict__ o) {
    int i = (blockIdx.x * blockDim.x + threadIdx.x) * 8;
    f32x4 a = *(const f32x4*)(emb + i);
    f32x4 b = *(const f32x4*)(emb + i + 4);
    short8 r;
#pragma unroll
    for (int j = 0; j < 4; ++j) { r[j] = bf16bits(a[j]); r[4 + j] = bf16bits(b[j]); }
    *(short8*)(o + i) = r;
}

// Block: 256 rows x 64 cols; wave w owns cols [w*16,+16) x ALL 256 rows
// (minimal W fetch: each W row read by exactly one block; store amp 1.08).
// THIS ROUND: the unexplored quadrant = HIGH occupancy (PHK=32 -> 32 KB LDS,
// VGPR<=128 -> 4 blocks/CU, 16 waves) + COUNTED vmcnt barriers (T4): each
// phase-end waits vmcnt(2) for loads issued a FULL phase earlier; the
// just-issued B(p+2) HBM load is never drained. No sched_barrier(0)
// (round-10 suspect). Swizzle: round-9 formula (measured 0 conflicts).
// Stores: round-7 epilogue (measured amp 1.08; barrier-aligned waves).
__global__ __launch_bounds__(256, 4) void gate_gemm(GemmParams P,
                                                    const unsigned short* __restrict__ embw,
                                                    float* __restrict__ out)
{
    constexpr int kStarts[11] = {0, 1728, 1792, 38656, 38720, 75584,
                                 75648, 112512, 112576, 120576, 120581};
    __shared__ unsigned short Atile[2][MROWS * PHK];   // 2 x 16 KB

    const int t    = threadIdx.x;
    const int lane = t & 63;
    const int wave = t >> 6;
    const int lr   = lane & 15;   // frag col (B/C) / frag row (A)
    const int lg   = lane >> 4;   // k-group / C row-group

    // This lane's single output column
    const int  n     = blockIdx.x * 64 + wave * 16 + lr;
    const bool valid = n < NTOT;
    const int  nc    = valid ? n : NTOT - 1;
    int tt = 0;
#pragma unroll
    for (int i = 1; i < 10; ++i) tt += (nc >= kStarts[i]);
    const int rr = nc - kStarts[tt];
    const float* wrow = P.W[tt] + (size_t)rr * GATE + lg * 8;
    const float pv = P.p[tt][rr];
    const float bv = P.bias[tt][rr];

    // ---- A staging (round-9-verified, 0 conflicts): pre-swizzled global
    // source, linear LDS dest. 16B-unit u = i*256+t: row = i*64+(t>>2),
    // slotw = t&3; holds embw[row][p*32 + ((slotw ^ ((row>>1)&3))*8) ..+8].
    const int srow0 = t >> 2;
    const int sslot = (t & 3) ^ ((t >> 3) & 3);
    const unsigned short* asrc0 = embw + (size_t)srow0 * GATE + sslot * 8;

    auto stage = [&](int buf, int p) {
#pragma unroll
        for (int i = 0; i < 4; ++i) {
            const unsigned short* src = asrc0 + (size_t)i * 64 * GATE + p * PHK;
            unsigned short* dst = &Atile[buf][(size_t)(i * 256 + t) * 8];
            __builtin_amdgcn_global_load_lds(
                (const __attribute__((address_space(1))) void*)src,
                (__attribute__((address_space(3))) void*)dst, 16, 0, 0);
        }
    };

    // A read: row = mf*16 + lr -> slot = lg ^ ((lr>>1)&3); lanes lr, lr+8
    // alias 2-way per bank-quad = free (m136; round-9 counter = 0).
    const int axor = (lr >> 1) & 3;

    f32x4 acc[16];
#pragma unroll
    for (int i = 0; i < 16; ++i) acc[i] = (f32x4){0.f, 0.f, 0.f, 0.f};

    // Rotating 3-set B raw registers (24 VGPR); converted at use.
    f32x4 Braw[3][2];
    auto loadB = [&](int s, int p) {
        Braw[s][0] = *(const f32x4*)(wrow + p * PHK);
        Braw[s][1] = *(const f32x4*)(wrow + p * PHK + 4);
    };

    // Prologue: A phase 0; B phases 0,1. One full drain, one barrier.
    stage(0, 0);
    loadB(0, 0);
    loadB(1, 1);
    asm volatile("s_waitcnt vmcnt(0)" ::: "memory");
    __builtin_amdgcn_s_barrier();

#pragma unroll
    for (int p = 0; p < 16; ++p) {
        const int buf = p & 1;
        if (p + 1 < 16) stage(buf ^ 1, p + 1);      // 4 VMEM (L2-hot embw)
        if (p + 2 < 16) loadB((p + 2) % 3, p + 2);  // 2 VMEM (HBM, 2 phases early)

        short8 bfrag;
        {
            const f32x4 lo = Braw[p % 3][0];
            const f32x4 hi = Braw[p % 3][1];
#pragma unroll
            for (int j = 0; j < 4; ++j) {
                bfrag[j]     = bf16bits(lo[j]);
                bfrag[4 + j] = bf16bits(hi[j]);
            }
        }

#pragma unroll
        for (int mf = 0; mf < 16; ++mf) {
            short8 af = *(const short8*)(
                &Atile[buf][(mf * 16 + lr) * PHK + (lg ^ axor) * 8]);
            acc[mf] = __builtin_amdgcn_mfma_f32_16x16x32_bf16(af, bfrag, acc[mf], 0, 0, 0);
        }

        if (p < 15) {
            // Ledger (in-order; no stores in loop): outstanding =
            // [loadB(p+1):2][stage(p+1):4][loadB(p+2):2] -> vmcnt(2)
            // retires through stage(p+1), leaves loadB(p+2) in flight.
            if (p < 14) asm volatile("s_waitcnt vmcnt(2)" ::: "memory");
            else        asm volatile("s_waitcnt vmcnt(0)" ::: "memory");
            __builtin_amdgcn_s_barrier();
        }
    }

    // Epilogue (round-7-identical; measured write amp 1.08).
    // C/D map: col = lane&15, row = (lane>>4)*4 + reg.
    if (valid) {
        float* ocol = out + n;
#pragma unroll
        for (int mf = 0; mf < 16; ++mf) {
            const int m0 = mf * 16 + lg * 4;
#pragma unroll
            for (int q = 0; q < 4; ++q) {
                float x   = acc[mf][q] + bv;
                float e   = __expf(-x);
                float eta = __builtin_amdgcn_rcpf(1.0f + e);
                ocol[(size_t)(m0 + q) * NTOT] = eta * pv;
            }
        }
    }
}

extern "C" void kernel_launch(void* const* d_in, const int* in_sizes, int n_in,
                              void* d_out, int out_size, void* d_ws, size_t ws_size,
                              hipStream_t stream) {
    const float* emb = (const float*)d_in[0];
    GemmParams P;
    for (int i = 0; i < 10; ++i) {
        P.p[i]    = (const float*)d_in[1 + 3 * i];
        P.W[i]    = (const float*)d_in[2 + 3 * i];
        P.bias[i] = (const float*)d_in[3 + 3 * i];
    }

    unsigned short* embw = (unsigned short*)d_ws;   // 256 KB, L2-resident
    emb_to_bf16<<<(MROWS * GATE) / (256 * 8), 256, 0, stream>>>(emb, embw);

    int nblocks = (NTOT + 63) / 64;   // 1885
    gate_gemm<<<nblocks, 256, 0, stream>>>(P, embw, (float*)d_out);
}